// Round 3
// baseline (922.052 us; speedup 1.0000x reference)
//
#include <hip/hip_runtime.h>

// Problem constants: B=32, S=512, L=20, T=16, E=300, H=128, D=128, V=50000

// ---------------------------------------------------------------------------
// K1: sentence embedding mean.  grid = B*S blocks, 128 threads.
// sent[bs][0:300] = mean over 20 words of embed_table rows.
// ---------------------------------------------------------------------------
__global__ __launch_bounds__(128) void k_sent_mean(
    const int* __restrict__ wid, const float* __restrict__ emb,
    float* __restrict__ sent)
{
  const int bs = blockIdx.x;
  const int tid = threadIdx.x;
  const int* w = wid + (size_t)bs * 20;
  float a0 = 0.f, a1 = 0.f, a2 = 0.f;
  for (int l = 0; l < 20; ++l) {
    const float* row = emb + (size_t)w[l] * 300;
    a0 += row[tid];
    a1 += row[tid + 128];
    if (tid < 44) a2 += row[tid + 256];
  }
  const float inv = 1.0f / 20.0f;
  float* o = sent + (size_t)bs * 300;
  o[tid] = a0 * inv;
  o[tid + 128] = a1 * inv;
  if (tid < 44) o[tid + 256] = a2 * inv;
}

// ---------------------------------------------------------------------------
// K2: generic fp32 tiled GEMM.  C[M,N] = A[M,K] @ B + bias, optional relu.
// BT=true : B is (N,K) row-major (torch weight, K contiguous)  -> C=A@B^T
// BT=false: B is (K,N) row-major (N contiguous)                -> C=A@B
// 64x64 tile, 256 threads, 4x4 micro-tile per thread, K chunked by 64.
// N must be a multiple of 64 (true for all call sites); M,K arbitrary.
// ---------------------------------------------------------------------------
template<bool BT, int ACT>
__global__ __launch_bounds__(256) void k_gemm(
    const int M, const int N, const int K,
    const float* __restrict__ A, const int lda,
    const float* __restrict__ Bm, const int ldb,
    float* __restrict__ C, const int ldc,
    const float* __restrict__ bias)
{
  (void)N;
  __shared__ float As[64][68];
  __shared__ float Bs[64][68];
  const int tid = threadIdx.x;
  const int m0 = blockIdx.x * 64;
  const int n0 = blockIdx.y * 64;
  const int tx = tid & 15;
  const int ty = tid >> 4;
  float acc[4][4] = {};

  for (int kc = 0; kc < K; kc += 64) {
    const int kb = (K - kc < 64) ? (K - kc) : 64;
    // --- stage A tile: As[m][k] ---
    #pragma unroll
    for (int r = 0; r < 4; ++r) {
      const int m = r * 16 + ty;
      const int k4 = tx * 4;
      float4 v = make_float4(0.f, 0.f, 0.f, 0.f);
      if (m0 + m < M) {
        const float* ap = A + (size_t)(m0 + m) * lda + kc;
        if (k4 + 4 <= kb) {
          v = *(const float4*)(ap + k4);
        } else {
          float t0 = (k4 + 0 < kb) ? ap[k4 + 0] : 0.f;
          float t1 = (k4 + 1 < kb) ? ap[k4 + 1] : 0.f;
          float t2 = (k4 + 2 < kb) ? ap[k4 + 2] : 0.f;
          float t3 = (k4 + 3 < kb) ? ap[k4 + 3] : 0.f;
          v = make_float4(t0, t1, t2, t3);
        }
      }
      *(float4*)&As[m][k4] = v;
    }
    // --- stage B tile: Bs[k][n] ---
    if (BT) {
      #pragma unroll
      for (int r = 0; r < 4; ++r) {
        const int n = r * 16 + ty;           // n0+n < N guaranteed (N % 64 == 0)
        const int k4 = tx * 4;
        float4 v = make_float4(0.f, 0.f, 0.f, 0.f);
        const float* bp = Bm + (size_t)(n0 + n) * ldb + kc;
        if (k4 + 4 <= kb) {
          v = *(const float4*)(bp + k4);
        } else {
          float t0 = (k4 + 0 < kb) ? bp[k4 + 0] : 0.f;
          float t1 = (k4 + 1 < kb) ? bp[k4 + 1] : 0.f;
          float t2 = (k4 + 2 < kb) ? bp[k4 + 2] : 0.f;
          float t3 = (k4 + 3 < kb) ? bp[k4 + 3] : 0.f;
          v = make_float4(t0, t1, t2, t3);
        }
        Bs[k4 + 0][n] = v.x;
        Bs[k4 + 1][n] = v.y;
        Bs[k4 + 2][n] = v.z;
        Bs[k4 + 3][n] = v.w;
      }
    } else {
      #pragma unroll
      for (int r = 0; r < 4; ++r) {
        const int kk = r * 16 + ty;
        const int n4 = tx * 4;
        float4 v = make_float4(0.f, 0.f, 0.f, 0.f);
        if (kk < kb) v = *(const float4*)(Bm + (size_t)(kc + kk) * ldb + n0 + n4);
        *(float4*)&Bs[kk][n4] = v;
      }
    }
    __syncthreads();
    #pragma unroll 4
    for (int kk = 0; kk < kb; ++kk) {
      const float4 bv = *(const float4*)&Bs[kk][tx * 4];
      #pragma unroll
      for (int i = 0; i < 4; ++i) {
        const float a = As[ty * 4 + i][kk];
        acc[i][0] = fmaf(a, bv.x, acc[i][0]);
        acc[i][1] = fmaf(a, bv.y, acc[i][1]);
        acc[i][2] = fmaf(a, bv.z, acc[i][2]);
        acc[i][3] = fmaf(a, bv.w, acc[i][3]);
      }
    }
    __syncthreads();
  }

  float bv4[4] = {0.f, 0.f, 0.f, 0.f};
  if (bias != nullptr) {
    #pragma unroll
    for (int j = 0; j < 4; ++j) bv4[j] = bias[n0 + tx * 4 + j];
  }
  #pragma unroll
  for (int i = 0; i < 4; ++i) {
    const int m = m0 + ty * 4 + i;
    if (m < M) {
      float4 o;
      o.x = acc[i][0] + bv4[0];
      o.y = acc[i][1] + bv4[1];
      o.z = acc[i][2] + bv4[2];
      o.w = acc[i][3] + bv4[3];
      if (ACT == 1) {
        o.x = fmaxf(o.x, 0.f); o.y = fmaxf(o.y, 0.f);
        o.z = fmaxf(o.z, 0.f); o.w = fmaxf(o.w, 0.f);
      }
      *(float4*)&C[(size_t)m * ldc + n0 + tx * 4] = o;
    }
  }
}

// ---------------------------------------------------------------------------
// K3: GRU recurrence, one block per (batch, direction).  grid = 64, 768 thr.
// Wh is register-resident: thread (t = tid%384, half = tid/384) holds
// Wh[t][half*64 .. half*64+63] in 16 float4 regs.  h lives in LDS.
// gi (input gates incl. bi) is precomputed by K2.
// Torch GRU: r=sig(gi_r+gh_r); z=sig(gi_z+gh_z); n=tanh(gi_n + r*gh_n);
//            h' = (1-z)*n + z*h   (gh includes bh).
// ---------------------------------------------------------------------------
__global__ __launch_bounds__(768) void k_gru(
    const float* __restrict__ gi_f, const float* __restrict__ gi_b,
    const float* __restrict__ Wh_f, const float* __restrict__ Wh_b,
    const float* __restrict__ bh_f, const float* __restrict__ bh_b,
    float* __restrict__ srep, float* __restrict__ hfin)
{
  const int dir = blockIdx.x & 1;
  const int b = blockIdx.x >> 1;
  const float* gi = dir ? gi_b : gi_f;
  const float* Wh = dir ? Wh_b : Wh_f;
  const float* bh = dir ? bh_b : bh_f;

  const int tid = threadIdx.x;
  const int half = (tid >= 384) ? 1 : 0;   // waves 0-5: half 0, waves 6-11: half 1
  const int t = tid - half * 384;

  __shared__ __align__(16) float hlds[128];
  __shared__ float part[2][384];

  float4 w[16];
  const float* wrow = Wh + (size_t)t * 128 + half * 64;
  #pragma unroll
  for (int kk = 0; kk < 16; ++kk) w[kk] = *(const float4*)(wrow + kk * 4);
  const float bh_t = half ? 0.f : bh[t];

  if (tid < 128) hlds[tid] = 0.f;
  __syncthreads();

  const float4* h4 = (const float4*)hlds + half * 16;

  for (int s = 0; s < 512; ++s) {
    const int seq = dir ? (511 - s) : s;
    float a0 = bh_t, a1 = 0.f, a2 = 0.f, a3 = 0.f;
    #pragma unroll
    for (int kk = 0; kk < 16; ++kk) {
      const float4 hv = h4[kk];
      a0 = fmaf(w[kk].x, hv.x, a0);
      a1 = fmaf(w[kk].y, hv.y, a1);
      a2 = fmaf(w[kk].z, hv.z, a2);
      a3 = fmaf(w[kk].w, hv.w, a3);
    }
    part[half][t] = (a0 + a1) + (a2 + a3);
    __syncthreads();
    if (tid < 128) {
      const size_t base = ((size_t)(b * 512 + seq)) * 384;
      const float ghr = part[0][tid]       + part[1][tid];
      const float ghz = part[0][tid + 128] + part[1][tid + 128];
      const float ghn = part[0][tid + 256] + part[1][tid + 256];
      const float gir = gi[base + tid];
      const float giz = gi[base + 128 + tid];
      const float gin = gi[base + 256 + tid];
      const float r = 1.f / (1.f + expf(-(gir + ghr)));
      const float z = 1.f / (1.f + expf(-(giz + ghz)));
      const float n = tanhf(gin + r * ghn);
      const float hnew = (1.f - z) * n + z * hlds[tid];
      hlds[tid] = hnew;
      srep[((size_t)(b * 512 + seq)) * 256 + dir * 128 + tid] = hnew;
    }
    __syncthreads();
  }
  if (tid < 128) hfin[(size_t)dir * 4096 + (size_t)b * 128 + tid] = hlds[tid];
}

// ---------------------------------------------------------------------------
// K4: topic boundary diffs.  grid = B*T = 512, 256 threads.
// padded(i) = sent_rep[i-1] for 1<=i<=512 else 0 (1-based boundaries).
// tmat[b][t][0:128]   = pad(ends)[0:128]  - pad(starts-1)[0:128]
// tmat[b][t][128:256] = pad(starts)[128:] - pad(ends+1)[128:]
// ---------------------------------------------------------------------------
__global__ __launch_bounds__(256) void k_topic(
    const int* __restrict__ starts, const int* __restrict__ ends,
    const float* __restrict__ srep, float* __restrict__ tmat)
{
  const int bt = blockIdx.x;
  const int b = bt >> 4;
  const int st = starts[bt], en = ends[bt];
  const int j = threadIdx.x;
  float v;
  if (j < 128) {
    const float a = (en >= 1 && en <= 512) ? srep[((size_t)(b * 512 + en - 1)) * 256 + j] : 0.f;
    const float c = (st - 1 >= 1 && st - 1 <= 512) ? srep[((size_t)(b * 512 + st - 2)) * 256 + j] : 0.f;
    v = a - c;
  } else {
    const float a = (st >= 1 && st <= 512) ? srep[((size_t)(b * 512 + st - 1)) * 256 + j] : 0.f;
    const float c = (en + 1 >= 1 && en + 1 <= 512) ? srep[((size_t)(b * 512 + en)) * 256 + j] : 0.f;
    v = a - c;
  }
  tmat[(size_t)bt * 256 + j] = v;
}

// ---------------------------------------------------------------------------
// K6: attention scores + context + assemble decoder input.
// grid = B*S, 256 threads.  ds = dot(tanh(sentpart+docpart), v_att);
// ts = dot(tanh(sentpart+topicpart), v_att);  weights = scores/sum;
// inp[bs] = [sent_rep[bs] (256) | dw*doc_rep[b] + tw*topic_mat[b][tp] (256)].
// inp aliases sentpart in-place (reads finish before writes, barrier-separated).
// ---------------------------------------------------------------------------
__global__ __launch_bounds__(256) void k_scores(
    const float* spart, const float* __restrict__ docp, const float* __restrict__ topp,
    const float* __restrict__ v_att, const float* __restrict__ srep,
    const float* __restrict__ docrep, const float* __restrict__ tmat,
    const int* __restrict__ s2t, float* inp)
{
  const int bs = blockIdx.x;
  const int b = bs >> 9;
  const int tid = threadIdx.x;
  const int tp = s2t[bs];
  const float* sp = spart + (size_t)bs * 512;
  const float* dp = docp + (size_t)b * 512;
  const float* tq = topp + ((size_t)(b * 16 + tp)) * 512;
  float ds = 0.f, ts = 0.f;
  #pragma unroll
  for (int r = 0; r < 2; ++r) {
    const int o = tid + r * 256;
    const float s0 = sp[o], v = v_att[o];
    ds += tanhf(s0 + dp[o]) * v;
    ts += tanhf(s0 + tq[o]) * v;
  }
  #pragma unroll
  for (int off = 32; off; off >>= 1) {
    ds += __shfl_down(ds, off);
    ts += __shfl_down(ts, off);
  }
  __shared__ float rds[4], rts[4], wsh[2];
  const int wv = tid >> 6, ln = tid & 63;
  if (ln == 0) { rds[wv] = ds; rts[wv] = ts; }
  __syncthreads();
  if (tid == 0) {
    const float D = rds[0] + rds[1] + rds[2] + rds[3];
    const float T = rts[0] + rts[1] + rts[2] + rts[3];
    const float sum = D + T;
    wsh[0] = D / sum;
    wsh[1] = T / sum;
  }
  __syncthreads();
  const float dw = wsh[0], tw = wsh[1];
  const float sr = srep[(size_t)bs * 256 + tid];
  const float ctx = dw * docrep[(size_t)b * 256 + tid]
                  + tw * tmat[((size_t)(b * 16 + tp)) * 256 + tid];
  float* op = inp + (size_t)bs * 512;
  op[tid] = sr;
  op[256 + tid] = ctx;
}

// ---------------------------------------------------------------------------
// K8: logits[bs] = dot(hbuf[bs], W2) + b2.  grid = B*S, 64 threads (1 wave).
// ---------------------------------------------------------------------------
__global__ __launch_bounds__(64) void k_logits(
    const float* __restrict__ hbuf, const float* __restrict__ W2,
    const float* __restrict__ b2, float* __restrict__ out)
{
  const int bs = blockIdx.x;
  const int ln = threadIdx.x;
  const float* h = hbuf + (size_t)bs * 128;
  float a = fmaf(h[ln], W2[ln], h[ln + 64] * W2[ln + 64]);
  #pragma unroll
  for (int off = 32; off; off >>= 1) a += __shfl_down(a, off);
  if (ln == 0) out[bs] = a + b2[0];
}

// ---------------------------------------------------------------------------
extern "C" void kernel_launch(void* const* d_in, const int* in_sizes, int n_in,
                              void* d_out, int out_size, void* d_ws, size_t ws_size,
                              hipStream_t stream)
{
  (void)in_sizes; (void)n_in; (void)out_size;

  const int*   word_ids = (const int*)d_in[0];
  const int*   starts   = (const int*)d_in[1];
  const int*   ends     = (const int*)d_in[2];
  const int*   s2t      = (const int*)d_in[3];
  const float* emb      = (const float*)d_in[4];
  const float* Wi_f     = (const float*)d_in[5];
  const float* Wh_f     = (const float*)d_in[6];
  const float* bi_f     = (const float*)d_in[7];
  const float* bh_f     = (const float*)d_in[8];
  const float* Wi_b     = (const float*)d_in[9];
  const float* Wh_b     = (const float*)d_in[10];
  const float* bi_b     = (const float*)d_in[11];
  const float* bh_b     = (const float*)d_in[12];
  const float* W_att    = (const float*)d_in[13];
  const float* v_att    = (const float*)d_in[14];
  const float* W1       = (const float*)d_in[15];
  const float* b1       = (const float*)d_in[16];
  const float* W2       = (const float*)d_in[17];
  const float* b2       = (const float*)d_in[18];
  float* out = (float*)d_out;

  // Workspace layout (bytes).  Aliasing:
  //   spart/inp (33.6MB) overlays gi_f+gi_b (50.3MB, dead after k_gru)
  //   hbuf (8.4MB) overlays sent (19.7MB, dead after the gi GEMMs)
  char* ws = (char*)d_ws;
  if (ws_size < 88440832u) return;   // insufficient scratch -> fail loudly
  float* sent  = (float*)(ws + 0);          // 16384*300*4 = 19,660,800
  float* gi_f  = (float*)(ws + 19660800);   // 16384*384*4 = 25,165,824
  float* gi_b  = (float*)(ws + 44826624);   // 25,165,824
  float* srep  = (float*)(ws + 69992448);   // 16384*256*4 = 16,777,216
  float* hfin  = (float*)(ws + 86769664);   // 2*32*128*4  = 32,768  (== doc_rep flat!)
  float* tmat  = (float*)(ws + 86802432);   // 32*16*256*4 = 524,288
  float* docp  = (float*)(ws + 87326720);   // 32*512*4    = 65,536
  float* topp  = (float*)(ws + 87392256);   // 512*512*4   = 1,048,576 -> end 88,440,832
  float* spart = (float*)(ws + 19660800);   // alias gi_f/gi_b
  float* hbuf  = (float*)(ws + 0);          // alias sent

  // 1) sentence means
  k_sent_mean<<<16384, 128, 0, stream>>>(word_ids, emb, sent);
  // 2) input gates (parallel over all steps): gi = sent @ Wi^T + bi
  k_gemm<true, 0><<<dim3(256, 6), 256, 0, stream>>>(16384, 384, 300, sent, 300, Wi_f, 300, gi_f, 384, bi_f);
  k_gemm<true, 0><<<dim3(256, 6), 256, 0, stream>>>(16384, 384, 300, sent, 300, Wi_b, 300, gi_b, 384, bi_b);
  // 3) bidirectional GRU recurrence -> sent_rep (B,S,2H), hfin (2,B,H)
  k_gru<<<64, 768, 0, stream>>>(gi_f, gi_b, Wh_f, Wh_b, bh_f, bh_b, srep, hfin);
  // 4) topic boundary matrix
  k_topic<<<512, 256, 0, stream>>>(starts, ends, srep, tmat);
  // 5) attention partial projections (cat@W_att split by halves of W_att rows)
  k_gemm<false, 0><<<dim3(256, 8), 256, 0, stream>>>(16384, 512, 256, srep, 256, W_att + 256 * 512, 512, spart, 512, nullptr);
  k_gemm<false, 0><<<dim3(1, 8),   256, 0, stream>>>(32,    512, 256, hfin, 256, W_att,            512, docp,  512, nullptr);
  k_gemm<false, 0><<<dim3(8, 8),   256, 0, stream>>>(512,   512, 256, tmat, 256, W_att,            512, topp,  512, nullptr);
  // 6) scores -> weights -> context -> decoder input (in-place over spart)
  k_scores<<<16384, 256, 0, stream>>>(spart, docp, topp, v_att, srep, hfin, tmat, s2t, spart);
  // 7) h = relu(inp @ W1^T + b1)
  k_gemm<true, 1><<<dim3(256, 2), 256, 0, stream>>>(16384, 128, 512, spart, 512, W1, 512, hbuf, 128, b1);
  // 8) logits
  k_logits<<<16384, 64, 0, stream>>>(hbuf, W2, b2, out);
}

// Round 4
// 863.396 us; speedup vs baseline: 1.0679x; 1.0679x over previous
//
#include <hip/hip_runtime.h>

// Problem constants: B=32, S=512, L=20, T=16, E=300, H=128, D=128, V=50000

// Raw workgroup barrier: orders LDS ops (lgkmcnt drain) but does NOT drain
// vmcnt — keeps prefetch global-loads and fire-and-forget stores in flight.
#define LDS_BARRIER() do {                                   \
    asm volatile("s_waitcnt lgkmcnt(0)" ::: "memory");       \
    __builtin_amdgcn_s_barrier();                            \
    asm volatile("" ::: "memory");                           \
  } while (0)

// ---------------------------------------------------------------------------
// K1: sentence embedding mean.  grid = B*S blocks, 128 threads.
// ---------------------------------------------------------------------------
__global__ __launch_bounds__(128) void k_sent_mean(
    const int* __restrict__ wid, const float* __restrict__ emb,
    float* __restrict__ sent)
{
  const int bs = blockIdx.x;
  const int tid = threadIdx.x;
  const int* w = wid + (size_t)bs * 20;
  float a0 = 0.f, a1 = 0.f, a2 = 0.f;
  for (int l = 0; l < 20; ++l) {
    const float* row = emb + (size_t)w[l] * 300;
    a0 += row[tid];
    a1 += row[tid + 128];
    if (tid < 44) a2 += row[tid + 256];
  }
  const float inv = 1.0f / 20.0f;
  float* o = sent + (size_t)bs * 300;
  o[tid] = a0 * inv;
  o[tid + 128] = a1 * inv;
  if (tid < 44) o[tid + 256] = a2 * inv;
}

// ---------------------------------------------------------------------------
// K2: generic fp32 tiled GEMM.  C[M,N] = A[M,K] @ B + bias, optional relu.
// BT=true : B is (N,K) row-major -> C=A@B^T ;  BT=false: B is (K,N) -> C=A@B
// 64x64 tile, 256 threads, 4x4 micro-tile, K chunked by 64.  N % 64 == 0.
// ---------------------------------------------------------------------------
template<bool BT, int ACT>
__global__ __launch_bounds__(256) void k_gemm(
    const int M, const int N, const int K,
    const float* __restrict__ A, const int lda,
    const float* __restrict__ Bm, const int ldb,
    float* __restrict__ C, const int ldc,
    const float* __restrict__ bias)
{
  (void)N;
  __shared__ float As[64][68];
  __shared__ float Bs[64][68];
  const int tid = threadIdx.x;
  const int m0 = blockIdx.x * 64;
  const int n0 = blockIdx.y * 64;
  const int tx = tid & 15;
  const int ty = tid >> 4;
  float acc[4][4] = {};

  for (int kc = 0; kc < K; kc += 64) {
    const int kb = (K - kc < 64) ? (K - kc) : 64;
    #pragma unroll
    for (int r = 0; r < 4; ++r) {
      const int m = r * 16 + ty;
      const int k4 = tx * 4;
      float4 v = make_float4(0.f, 0.f, 0.f, 0.f);
      if (m0 + m < M) {
        const float* ap = A + (size_t)(m0 + m) * lda + kc;
        if (k4 + 4 <= kb) {
          v = *(const float4*)(ap + k4);
        } else {
          float t0 = (k4 + 0 < kb) ? ap[k4 + 0] : 0.f;
          float t1 = (k4 + 1 < kb) ? ap[k4 + 1] : 0.f;
          float t2 = (k4 + 2 < kb) ? ap[k4 + 2] : 0.f;
          float t3 = (k4 + 3 < kb) ? ap[k4 + 3] : 0.f;
          v = make_float4(t0, t1, t2, t3);
        }
      }
      *(float4*)&As[m][k4] = v;
    }
    if (BT) {
      #pragma unroll
      for (int r = 0; r < 4; ++r) {
        const int n = r * 16 + ty;
        const int k4 = tx * 4;
        float4 v = make_float4(0.f, 0.f, 0.f, 0.f);
        const float* bp = Bm + (size_t)(n0 + n) * ldb + kc;
        if (k4 + 4 <= kb) {
          v = *(const float4*)(bp + k4);
        } else {
          float t0 = (k4 + 0 < kb) ? bp[k4 + 0] : 0.f;
          float t1 = (k4 + 1 < kb) ? bp[k4 + 1] : 0.f;
          float t2 = (k4 + 2 < kb) ? bp[k4 + 2] : 0.f;
          float t3 = (k4 + 3 < kb) ? bp[k4 + 3] : 0.f;
          v = make_float4(t0, t1, t2, t3);
        }
        Bs[k4 + 0][n] = v.x;
        Bs[k4 + 1][n] = v.y;
        Bs[k4 + 2][n] = v.z;
        Bs[k4 + 3][n] = v.w;
      }
    } else {
      #pragma unroll
      for (int r = 0; r < 4; ++r) {
        const int kk = r * 16 + ty;
        const int n4 = tx * 4;
        float4 v = make_float4(0.f, 0.f, 0.f, 0.f);
        if (kk < kb) v = *(const float4*)(Bm + (size_t)(kc + kk) * ldb + n0 + n4);
        *(float4*)&Bs[kk][n4] = v;
      }
    }
    __syncthreads();
    #pragma unroll 4
    for (int kk = 0; kk < kb; ++kk) {
      const float4 bv = *(const float4*)&Bs[kk][tx * 4];
      #pragma unroll
      for (int i = 0; i < 4; ++i) {
        const float a = As[ty * 4 + i][kk];
        acc[i][0] = fmaf(a, bv.x, acc[i][0]);
        acc[i][1] = fmaf(a, bv.y, acc[i][1]);
        acc[i][2] = fmaf(a, bv.z, acc[i][2]);
        acc[i][3] = fmaf(a, bv.w, acc[i][3]);
      }
    }
    __syncthreads();
  }

  float bv4[4] = {0.f, 0.f, 0.f, 0.f};
  if (bias != nullptr) {
    #pragma unroll
    for (int j = 0; j < 4; ++j) bv4[j] = bias[n0 + tx * 4 + j];
  }
  #pragma unroll
  for (int i = 0; i < 4; ++i) {
    const int m = m0 + ty * 4 + i;
    if (m < M) {
      float4 o;
      o.x = acc[i][0] + bv4[0];
      o.y = acc[i][1] + bv4[1];
      o.z = acc[i][2] + bv4[2];
      o.w = acc[i][3] + bv4[3];
      if (ACT == 1) {
        o.x = fmaxf(o.x, 0.f); o.y = fmaxf(o.y, 0.f);
        o.z = fmaxf(o.z, 0.f); o.w = fmaxf(o.w, 0.f);
      }
      *(float4*)&C[(size_t)m * ldc + n0 + tx * 4] = o;
    }
  }
}

// ---------------------------------------------------------------------------
// K3: GRU recurrence, one block per (batch, direction).  grid = 64, 768 thr.
// Wh register-resident (thread t=tid%384, half=tid/384 holds 64 floats of
// row t).  h in LDS.  gi staged into LDS in double-buffered 32-step chunks:
// global loads issued at chunk start, ds_write at chunk end (latency hidden
// under 32 steps of compute).  Per-step barriers are raw s_barrier +
// lgkmcnt(0) only — no vmcnt drain, so prefetch loads and srep stores stay
// in flight.  Step math is bit-identical to the validated round-2 kernel.
// ---------------------------------------------------------------------------
__global__ __launch_bounds__(768, 3) void k_gru(
    const float* __restrict__ gi_f, const float* __restrict__ gi_b,
    const float* __restrict__ Wh_f, const float* __restrict__ Wh_b,
    const float* __restrict__ bh_f, const float* __restrict__ bh_b,
    float* __restrict__ srep, float* __restrict__ hfin)
{
  const int dir = blockIdx.x & 1;
  const int b = blockIdx.x >> 1;
  const float* gi = (dir ? gi_b : gi_f) + (size_t)b * 512 * 384;
  const float* Wh = dir ? Wh_b : Wh_f;
  const float* bh = dir ? bh_b : bh_f;

  const int tid = threadIdx.x;
  const int half = (tid >= 384) ? 1 : 0;   // waves 0-5: half 0, 6-11: half 1
  const int t = tid - half * 384;

  __shared__ __align__(16) float hlds[128];
  __shared__ float part[2][384];
  __shared__ __align__(16) float gis[2][32 * 384];   // 2 x 48 KB

  float4 w[16];
  const float* wrow = Wh + (size_t)t * 128 + half * 64;
  #pragma unroll
  for (int kk = 0; kk < 16; ++kk) w[kk] = *(const float4*)(wrow + kk * 4);
  const float bh_t = half ? 0.f : bh[t];

  // prologue: stage chunk 0 synchronously
  {
    const int lo0 = dir ? 480 : 0;
    const float4* g4 = (const float4*)gi + lo0 * 96;   // 96 float4 per row
    float4* l4 = (float4*)gis[0];
    #pragma unroll
    for (int j = 0; j < 4; ++j) l4[j * 768 + tid] = g4[j * 768 + tid];
  }
  if (tid < 128) hlds[tid] = 0.f;
  LDS_BARRIER();

  const float4* h4 = (const float4*)hlds + half * 16;
  float4 stg[4];

  for (int c = 0; c < 16; ++c) {
    const int buf = c & 1;
    const int lo = dir ? (480 - 32 * c) : (32 * c);
    // issue next chunk's global loads (non-blocking; consumed at chunk end)
    if (c < 15) {
      const int lon = dir ? (480 - 32 * (c + 1)) : (32 * (c + 1));
      const float4* g4 = (const float4*)gi + lon * 96;
      #pragma unroll
      for (int j = 0; j < 4; ++j) stg[j] = g4[j * 768 + tid];
    }

    for (int i = 0; i < 32; ++i) {
      const int sloc = dir ? (31 - i) : i;    // row within chunk
      const int seq = lo + sloc;              // absolute sequence index

      float a0 = bh_t, a1 = 0.f, a2 = 0.f, a3 = 0.f;
      #pragma unroll
      for (int kk = 0; kk < 16; ++kk) {
        const float4 hv = h4[kk];
        a0 = fmaf(w[kk].x, hv.x, a0);
        a1 = fmaf(w[kk].y, hv.y, a1);
        a2 = fmaf(w[kk].z, hv.z, a2);
        a3 = fmaf(w[kk].w, hv.w, a3);
      }
      part[half][t] = (a0 + a1) + (a2 + a3);
      LDS_BARRIER();

      if (tid < 128) {
        const float* grow = &gis[buf][sloc * 384];
        const float ghr = part[0][tid]       + part[1][tid];
        const float ghz = part[0][tid + 128] + part[1][tid + 128];
        const float ghn = part[0][tid + 256] + part[1][tid + 256];
        const float gir = grow[tid];
        const float giz = grow[tid + 128];
        const float gin = grow[tid + 256];
        const float r = 1.f / (1.f + expf(-(gir + ghr)));
        const float z = 1.f / (1.f + expf(-(giz + ghz)));
        const float n = tanhf(gin + r * ghn);
        const float hnew = (1.f - z) * n + z * hlds[tid];
        hlds[tid] = hnew;
        srep[((size_t)(b * 512 + seq)) * 256 + dir * 128 + tid] = hnew;
      }
      LDS_BARRIER();
    }

    // write staged next chunk into the buffer we just finished reading
    if (c < 15) {
      float4* l4 = (float4*)gis[buf ^ 1];
      #pragma unroll
      for (int j = 0; j < 4; ++j) l4[j * 768 + tid] = stg[j];
      LDS_BARRIER();
    }
  }
  if (tid < 128) hfin[(size_t)dir * 4096 + (size_t)b * 128 + tid] = hlds[tid];
}

// ---------------------------------------------------------------------------
// K4: topic boundary diffs.  grid = B*T = 512, 256 threads.
// ---------------------------------------------------------------------------
__global__ __launch_bounds__(256) void k_topic(
    const int* __restrict__ starts, const int* __restrict__ ends,
    const float* __restrict__ srep, float* __restrict__ tmat)
{
  const int bt = blockIdx.x;
  const int b = bt >> 4;
  const int st = starts[bt], en = ends[bt];
  const int j = threadIdx.x;
  float v;
  if (j < 128) {
    const float a = (en >= 1 && en <= 512) ? srep[((size_t)(b * 512 + en - 1)) * 256 + j] : 0.f;
    const float c = (st - 1 >= 1 && st - 1 <= 512) ? srep[((size_t)(b * 512 + st - 2)) * 256 + j] : 0.f;
    v = a - c;
  } else {
    const float a = (st >= 1 && st <= 512) ? srep[((size_t)(b * 512 + st - 1)) * 256 + j] : 0.f;
    const float c = (en + 1 >= 1 && en + 1 <= 512) ? srep[((size_t)(b * 512 + en)) * 256 + j] : 0.f;
    v = a - c;
  }
  tmat[(size_t)bt * 256 + j] = v;
}

// ---------------------------------------------------------------------------
// K6: attention scores + context + assemble decoder input.  grid = B*S.
// ---------------------------------------------------------------------------
__global__ __launch_bounds__(256) void k_scores(
    const float* spart, const float* __restrict__ docp, const float* __restrict__ topp,
    const float* __restrict__ v_att, const float* __restrict__ srep,
    const float* __restrict__ docrep, const float* __restrict__ tmat,
    const int* __restrict__ s2t, float* inp)
{
  const int bs = blockIdx.x;
  const int b = bs >> 9;
  const int tid = threadIdx.x;
  const int tp = s2t[bs];
  const float* sp = spart + (size_t)bs * 512;
  const float* dp = docp + (size_t)b * 512;
  const float* tq = topp + ((size_t)(b * 16 + tp)) * 512;
  float ds = 0.f, ts = 0.f;
  #pragma unroll
  for (int r = 0; r < 2; ++r) {
    const int o = tid + r * 256;
    const float s0 = sp[o], v = v_att[o];
    ds += tanhf(s0 + dp[o]) * v;
    ts += tanhf(s0 + tq[o]) * v;
  }
  #pragma unroll
  for (int off = 32; off; off >>= 1) {
    ds += __shfl_down(ds, off);
    ts += __shfl_down(ts, off);
  }
  __shared__ float rds[4], rts[4], wsh[2];
  const int wv = tid >> 6, ln = tid & 63;
  if (ln == 0) { rds[wv] = ds; rts[wv] = ts; }
  __syncthreads();
  if (tid == 0) {
    const float D = rds[0] + rds[1] + rds[2] + rds[3];
    const float T = rts[0] + rts[1] + rts[2] + rts[3];
    const float sum = D + T;
    wsh[0] = D / sum;
    wsh[1] = T / sum;
  }
  __syncthreads();
  const float dw = wsh[0], tw = wsh[1];
  const float sr = srep[(size_t)bs * 256 + tid];
  const float ctx = dw * docrep[(size_t)b * 256 + tid]
                  + tw * tmat[((size_t)(b * 16 + tp)) * 256 + tid];
  float* op = inp + (size_t)bs * 512;
  op[tid] = sr;
  op[256 + tid] = ctx;
}

// ---------------------------------------------------------------------------
// K8: logits[bs] = dot(hbuf[bs], W2) + b2.  grid = B*S, 64 threads.
// ---------------------------------------------------------------------------
__global__ __launch_bounds__(64) void k_logits(
    const float* __restrict__ hbuf, const float* __restrict__ W2,
    const float* __restrict__ b2, float* __restrict__ out)
{
  const int bs = blockIdx.x;
  const int ln = threadIdx.x;
  const float* h = hbuf + (size_t)bs * 128;
  float a = fmaf(h[ln], W2[ln], h[ln + 64] * W2[ln + 64]);
  #pragma unroll
  for (int off = 32; off; off >>= 1) a += __shfl_down(a, off);
  if (ln == 0) out[bs] = a + b2[0];
}

// ---------------------------------------------------------------------------
extern "C" void kernel_launch(void* const* d_in, const int* in_sizes, int n_in,
                              void* d_out, int out_size, void* d_ws, size_t ws_size,
                              hipStream_t stream)
{
  (void)in_sizes; (void)n_in; (void)out_size;

  const int*   word_ids = (const int*)d_in[0];
  const int*   starts   = (const int*)d_in[1];
  const int*   ends     = (const int*)d_in[2];
  const int*   s2t      = (const int*)d_in[3];
  const float* emb      = (const float*)d_in[4];
  const float* Wi_f     = (const float*)d_in[5];
  const float* Wh_f     = (const float*)d_in[6];
  const float* bi_f     = (const float*)d_in[7];
  const float* bh_f     = (const float*)d_in[8];
  const float* Wi_b     = (const float*)d_in[9];
  const float* Wh_b     = (const float*)d_in[10];
  const float* bi_b     = (const float*)d_in[11];
  const float* bh_b     = (const float*)d_in[12];
  const float* W_att    = (const float*)d_in[13];
  const float* v_att    = (const float*)d_in[14];
  const float* W1       = (const float*)d_in[15];
  const float* b1       = (const float*)d_in[16];
  const float* W2       = (const float*)d_in[17];
  const float* b2       = (const float*)d_in[18];
  float* out = (float*)d_out;

  // Workspace layout (bytes).  Aliasing:
  //   spart/inp (33.6MB) overlays gi_f+gi_b (50.3MB, dead after k_gru)
  //   hbuf (8.4MB) overlays sent (19.7MB, dead after the gi GEMMs)
  char* ws = (char*)d_ws;
  if (ws_size < 88440832u) return;   // insufficient scratch -> fail loudly
  float* sent  = (float*)(ws + 0);          // 16384*300*4 = 19,660,800
  float* gi_f  = (float*)(ws + 19660800);   // 16384*384*4 = 25,165,824
  float* gi_b  = (float*)(ws + 44826624);   // 25,165,824
  float* srep  = (float*)(ws + 69992448);   // 16384*256*4 = 16,777,216
  float* hfin  = (float*)(ws + 86769664);   // 2*32*128*4  = 32,768  (== doc_rep flat)
  float* tmat  = (float*)(ws + 86802432);   // 32*16*256*4 = 524,288
  float* docp  = (float*)(ws + 87326720);   // 32*512*4    = 65,536
  float* topp  = (float*)(ws + 87392256);   // 512*512*4   = 1,048,576 -> end 88,440,832
  float* spart = (float*)(ws + 19660800);   // alias gi_f/gi_b
  float* hbuf  = (float*)(ws + 0);          // alias sent

  // 1) sentence means
  k_sent_mean<<<16384, 128, 0, stream>>>(word_ids, emb, sent);
  // 2) input gates (parallel over all steps): gi = sent @ Wi^T + bi
  k_gemm<true, 0><<<dim3(256, 6), 256, 0, stream>>>(16384, 384, 300, sent, 300, Wi_f, 300, gi_f, 384, bi_f);
  k_gemm<true, 0><<<dim3(256, 6), 256, 0, stream>>>(16384, 384, 300, sent, 300, Wi_b, 300, gi_b, 384, bi_b);
  // 3) bidirectional GRU recurrence -> sent_rep (B,S,2H), hfin (2,B,H)
  k_gru<<<64, 768, 0, stream>>>(gi_f, gi_b, Wh_f, Wh_b, bh_f, bh_b, srep, hfin);
  // 4) topic boundary matrix
  k_topic<<<512, 256, 0, stream>>>(starts, ends, srep, tmat);
  // 5) attention partial projections (cat@W_att split by halves of W_att rows)
  k_gemm<false, 0><<<dim3(256, 8), 256, 0, stream>>>(16384, 512, 256, srep, 256, W_att + 256 * 512, 512, spart, 512, nullptr);
  k_gemm<false, 0><<<dim3(1, 8),   256, 0, stream>>>(32,    512, 256, hfin, 256, W_att,            512, docp,  512, nullptr);
  k_gemm<false, 0><<<dim3(8, 8),   256, 0, stream>>>(512,   512, 256, tmat, 256, W_att,            512, topp,  512, nullptr);
  // 6) scores -> weights -> context -> decoder input (in-place over spart)
  k_scores<<<16384, 256, 0, stream>>>(spart, docp, topp, v_att, srep, hfin, tmat, s2t, spart);
  // 7) h = relu(inp @ W1^T + b1)
  k_gemm<true, 1><<<dim3(256, 2), 256, 0, stream>>>(16384, 128, 512, spart, 512, W1, 512, hbuf, 128, b1);
  // 8) logits
  k_logits<<<16384, 64, 0, stream>>>(hbuf, W2, b2, out);
}